// Round 2
// baseline (314.280 us; speedup 1.0000x reference)
//
#include <hip/hip_runtime.h>
#include <hip/hip_fp16.h>
#include <math.h>

#define FLT_BIG 3.402823466e38f
typedef unsigned int uint;
typedef unsigned short ushort;
typedef __attribute__((ext_vector_type(8))) short short8;   // 8 bf16 (4 VGPRs)
typedef __attribute__((ext_vector_type(4))) float floatx4;  // MFMA C/D frag

__device__ inline float bl(uint u) { return __uint_as_float(u << 16); }
__device__ inline float bh(uint u) { return __uint_as_float(u & 0xffff0000u); }
__device__ inline ushort f2bf(float f) {  // RNE
    uint u = __float_as_uint(f);
    return (ushort)((u + 0x7fffu + ((u >> 16) & 1u)) >> 16);
}
__device__ inline ushort f2h(float f) {   // fp16 RNE, 1 instr (v_cvt_f16_f32)
    return __half_as_ushort(__float2half(f));
}
// packed 2xfp16 dot with f32 accumulate: d = a.h0*b.h0 + a.h1*b.h1 + c
__device__ inline float dot2(uint a, uint b, float c) {
    float d;
    asm("v_dot2_f32_f16 %0, %1, %2, %3" : "=v"(d) : "v"(a), "v"(b), "v"(c));
    return d;
}

// ---------------------------------------------------------------- min(xyz)
__global__ void min_reduce_kernel(const float* __restrict__ xyz, int n, float* mn) {
    float m0 = FLT_BIG, m1 = FLT_BIG, m2 = FLT_BIG;
    for (int i = blockIdx.x * blockDim.x + threadIdx.x; i < n; i += gridDim.x * blockDim.x) {
        m0 = fminf(m0, xyz[3 * i + 0]);
        m1 = fminf(m1, xyz[3 * i + 1]);
        m2 = fminf(m2, xyz[3 * i + 2]);
    }
#pragma unroll
    for (int off = 32; off > 0; off >>= 1) {
        m0 = fminf(m0, __shfl_down(m0, off));
        m1 = fminf(m1, __shfl_down(m1, off));
        m2 = fminf(m2, __shfl_down(m2, off));
    }
    if ((threadIdx.x & 63) == 0) {
        // xyz >= 0 so float bits are monotone under signed int compare
        atomicMin((int*)&mn[0], __float_as_int(m0));
        atomicMin((int*)&mn[1], __float_as_int(m1));
        atomicMin((int*)&mn[2], __float_as_int(m2));
    }
}

// ---------------------------------------------------------------- prep (small)
// mn init; tables [idx][hd][c] -> [c][idx][hd]; rq/rk fp16 (dot2 operands),
// rv bf16 (unpacked via shift/and). W transposes -> bf16 for MFMA.
__global__ void prep_kernel(const float* __restrict__ W_qkv,
                            const float* __restrict__ W_proj,
                            const float* __restrict__ tq, const float* __restrict__ tk,
                            const float* __restrict__ tv,
                            ushort* __restrict__ wtqkv, ushort* __restrict__ wtproj,
                            ushort* __restrict__ rq, ushort* __restrict__ rk,
                            ushort* __restrict__ rv, float* mn) {
    int tid = blockIdx.x * 256 + threadIdx.x;
    if (tid < 3) mn[tid] = FLT_BIG;
    if (tid < 18432) {  // tables: 3*64*96
        int c = tid / 6144, rem = tid - c * 6144;
        int idx = rem / 96, hd = rem - idx * 96;
        int src = (idx * 96 + hd) * 3 + c;
        rq[tid] = f2h(tq[src]);
        rk[tid] = f2h(tk[src]);
        rv[tid] = f2bf(tv[src]);
    }
    if (tid < 27648) {  // WT_qkv[j][d] = W_qkv[d][j], j over 288
        int j = tid / 96, d = tid - j * 96;
        wtqkv[tid] = f2bf(W_qkv[d * 288 + j]);
    }
    if (tid < 9216) {  // WT_proj[j][d] = W_proj[d][j]
        int j = tid / 96, d = tid - j * 96;
        wtproj[tid] = f2bf(W_proj[d * 96 + j]);
    }
}

// ---------------------------------------------------------------- QKV MFMA GEMM
// feats fp32 (n x 96) @ WT^T + bias. q -> fp16 (x0.25), k -> fp16, v -> bf16.
// Wave job: 32 rows x 96 cols, K=96. Epilogue: per-wave LDS repack (pitch 112
// ushorts), uint4 coalesced stores. Verified frag layouts (m89/m91).
__global__ __launch_bounds__(256) void qkv_mfma_kernel(
    const float* __restrict__ A, const ushort* __restrict__ WT,
    const float* __restrict__ bias, uint4* __restrict__ qout4,
    uint4* __restrict__ kvout4, int n) {
    __shared__ ushort lds[4][32 * 112];
    const int wave = threadIdx.x >> 6, lane = threadIdx.x & 63;
    const int ch = blockIdx.y;
    const int m = lane & 15, q = lane >> 4;
    const int row0 = blockIdx.x * 128 + wave * 32;
    if (row0 >= n) return;

    const ushort* wbase = WT + ((size_t)ch * 96 + m) * 96 + q * 8;
    int r0 = row0 + m;      if (r0 > n - 1) r0 = n - 1;
    int r1 = row0 + 16 + m; if (r1 > n - 1) r1 = n - 1;
    const float4* A4 = (const float4*)A;

    floatx4 acc[2][6];
#pragma unroll
    for (int g = 0; g < 2; g++)
#pragma unroll
        for (int ct = 0; ct < 6; ct++) acc[g][ct] = (floatx4){0.f, 0.f, 0.f, 0.f};

#pragma unroll
    for (int kk4 = 0; kk4 < 24; kk4 += 8) {  // k offset in float4 units
        float4 fa = A4[(size_t)r0 * 24 + kk4 + q * 2];
        float4 fb = A4[(size_t)r0 * 24 + kk4 + q * 2 + 1];
        float4 ga = A4[(size_t)r1 * 24 + kk4 + q * 2];
        float4 gb = A4[(size_t)r1 * 24 + kk4 + q * 2 + 1];
        short8 a0, a1;
        a0[0] = f2bf(fa.x); a0[1] = f2bf(fa.y); a0[2] = f2bf(fa.z); a0[3] = f2bf(fa.w);
        a0[4] = f2bf(fb.x); a0[5] = f2bf(fb.y); a0[6] = f2bf(fb.z); a0[7] = f2bf(fb.w);
        a1[0] = f2bf(ga.x); a1[1] = f2bf(ga.y); a1[2] = f2bf(ga.z); a1[3] = f2bf(ga.w);
        a1[4] = f2bf(gb.x); a1[5] = f2bf(gb.y); a1[6] = f2bf(gb.z); a1[7] = f2bf(gb.w);
#pragma unroll
        for (int ct = 0; ct < 6; ct++) {
            short8 b = *(const short8*)(wbase + ct * 16 * 96 + kk4 * 4);
            acc[0][ct] = __builtin_amdgcn_mfma_f32_16x16x32_bf16(a0, b, acc[0][ct], 0, 0, 0);
            acc[1][ct] = __builtin_amdgcn_mfma_f32_16x16x32_bf16(a1, b, acc[1][ct], 0, 0, 0);
        }
    }

    ushort* L = lds[wave];
    const float sc = (ch == 0) ? 0.25f : 1.0f;
#pragma unroll
    for (int g = 0; g < 2; g++)
#pragma unroll
        for (int ct = 0; ct < 6; ct++) {
            float bv = bias[ch * 96 + ct * 16 + m];
#pragma unroll
            for (int r = 0; r < 4; r++) {
                int rowl = g * 16 + q * 4 + r;
                float y = (acc[g][ct][r] + bv) * sc;
                L[rowl * 112 + ct * 16 + m] = (ch == 2) ? f2bf(y) : f2h(y);
            }
        }
    // wave-internal LDS RAW: compiler inserts lgkmcnt wait, no barrier needed
    const int strideU4 = (ch == 0) ? 12 : 24;
    const int offU4 = (ch == 2) ? 12 : 0;
    uint4* dst = (ch == 0) ? qout4 : kvout4;
#pragma unroll
    for (int i = 0; i < 6; i++) {
        int idx = i * 64 + lane;  // 0..383 over 32 rows x 12 uint4
        int rowl = idx / 12, u4 = idx - rowl * 12;
        int grow = row0 + rowl;
        if (grow < n) {
            uint4 val = *(const uint4*)(L + rowl * 112 + u4 * 8);
            dst[(size_t)grow * strideU4 + offU4 + u4] = val;
        }
    }
}

// ---------------------------------------------------------------- proj MFMA GEMM
// x bf16 (n x 96) @ WT_proj^T + bias -> out fp32.
__global__ __launch_bounds__(256) void proj_mfma_kernel(
    const ushort* __restrict__ A, const ushort* __restrict__ WT,
    const float* __restrict__ bias, float* __restrict__ out, int n) {
    const int wave = threadIdx.x >> 6, lane = threadIdx.x & 63;
    const int m = lane & 15, q = lane >> 4;
    const int row0 = blockIdx.x * 128 + wave * 32;
    if (row0 >= n) return;

    const ushort* wbase = WT + (size_t)m * 96 + q * 8;
    int r0 = row0 + m;      if (r0 > n - 1) r0 = n - 1;
    int r1 = row0 + 16 + m; if (r1 > n - 1) r1 = n - 1;

    floatx4 acc[2][6];
#pragma unroll
    for (int g = 0; g < 2; g++)
#pragma unroll
        for (int ct = 0; ct < 6; ct++) acc[g][ct] = (floatx4){0.f, 0.f, 0.f, 0.f};

#pragma unroll
    for (int kk = 0; kk < 96; kk += 32) {
        short8 a0 = *(const short8*)(A + (size_t)r0 * 96 + q * 8 + kk);
        short8 a1 = *(const short8*)(A + (size_t)r1 * 96 + q * 8 + kk);
#pragma unroll
        for (int ct = 0; ct < 6; ct++) {
            short8 b = *(const short8*)(wbase + ct * 16 * 96 + kk);
            acc[0][ct] = __builtin_amdgcn_mfma_f32_16x16x32_bf16(a0, b, acc[0][ct], 0, 0, 0);
            acc[1][ct] = __builtin_amdgcn_mfma_f32_16x16x32_bf16(a1, b, acc[1][ct], 0, 0, 0);
        }
    }

#pragma unroll
    for (int g = 0; g < 2; g++)
#pragma unroll
        for (int ct = 0; ct < 6; ct++) {
            int col = ct * 16 + m;
            float bv = bias[col];
#pragma unroll
            for (int r = 0; r < 4; r++) {
                int row = row0 + g * 16 + q * 4 + r;
                if (row < n) out[(size_t)row * 96 + col] = acc[g][ct][r] + bv;
            }
        }
}

// ---------------------------------------------------------------- fused attention
// q fp16 (pre-scaled), kv row = k fp16[96] || v bf16[96] (384B).
// NO first barrier: every thread computes its own ridx (3x fmod/floor) and
// loads its own q fragment, so ALL ~22 global loads (kv gather, q, rv, rq, rk)
// are issuable back-to-back with no LDS/barrier dependency -> max MLP.
// Single barrier before the output phase (vs + smw visibility).
__global__ __launch_bounds__(192) void attn_kernel(
    const ushort* __restrict__ qh, const ushort* __restrict__ kv,
    const float* __restrict__ xyz, const int* __restrict__ index_1,
    const ushort* __restrict__ rq, const ushort* __restrict__ rk,
    const ushort* __restrict__ rv, const float* __restrict__ mn,
    const float* __restrict__ shiftp, ushort* __restrict__ xout, int n) {
    __shared__ float vs[2][16][100];     // v (+table_v bias), fp32, pitch 100
    __shared__ float smw[2][6][16];

    const int s = threadIdx.x / 96;
    const int tp = threadIdx.x - s * 96;
    const int p = blockIdx.x * 2 + s;
    const bool active = p < n;
    const int pc = active ? p : (n - 1);
    const int h = tp >> 4, e = tp & 15;

    const int jd = index_1[(size_t)pc * 16 + e];

    // ---- independent loads: kv fragments, q fragment (all issue immediately)
    const ushort* row = kv + (size_t)jd * 192;
    uint4 ka = *(const uint4*)(row + h * 16);
    uint4 kb = *(const uint4*)(row + h * 16 + 8);
    uint4 va = *(const uint4*)(row + 96 + h * 16);
    uint4 vb = *(const uint4*)(row + 96 + h * 16 + 8);
    const ushort* qrow = qh + (size_t)pc * 96 + h * 16;
    uint4 qa = *(const uint4*)qrow;
    uint4 qb = *(const uint4*)(qrow + 8);

    // ---- per-thread rel quantized index (no LDS, no barrier)
    int i0, i1, i2;
    {
        const float shift = shiftp[0];
        const float m0 = mn[0], m1 = mn[1], m2 = mn[2];
        const float* xp = xyz + 3 * (size_t)pc;
        const float* xj = xyz + 3 * (size_t)jd;
        float a0 = floorf(fmodf(xp[0] - m0 + shift, 4.0f) * 4.0f);
        float a1 = floorf(fmodf(xp[1] - m1 + shift, 4.0f) * 4.0f);
        float a2 = floorf(fmodf(xp[2] - m2 + shift, 4.0f) * 4.0f);
        float b0 = floorf(fmodf(xj[0] - m0 + shift, 4.0f) * 4.0f);
        float b1 = floorf(fmodf(xj[1] - m1 + shift, 4.0f) * 4.0f);
        float b2 = floorf(fmodf(xj[2] - m2 + shift, 4.0f) * 4.0f);
        i0 = (int)(a0 - b0) + 15;
        i1 = (int)(a1 - b1) + 15;
        i2 = (int)(a2 - b2) + 15;
    }

    // ---- fold table_v bias in regs, write v tile once (LDS)
    {
        const ushort* r0p = rv + (size_t)i0 * 96 + h * 16;
        const ushort* r1p = rv + (size_t)(64 + i1) * 96 + h * 16;
        const ushort* r2p = rv + (size_t)(128 + i2) * 96 + h * 16;
        uint4 u0a = *(const uint4*)r0p, u0b = *(const uint4*)(r0p + 8);
        uint4 u1a = *(const uint4*)r1p, u1b = *(const uint4*)(r1p + 8);
        uint4 u2a = *(const uint4*)r2p, u2b = *(const uint4*)(r2p + 8);
        float* vp = &vs[s][e][h * 16];
        *(float4*)(vp + 0) = make_float4(
            bl(va.x) + bl(u0a.x) + bl(u1a.x) + bl(u2a.x),
            bh(va.x) + bh(u0a.x) + bh(u1a.x) + bh(u2a.x),
            bl(va.y) + bl(u0a.y) + bl(u1a.y) + bl(u2a.y),
            bh(va.y) + bh(u0a.y) + bh(u1a.y) + bh(u2a.y));
        *(float4*)(vp + 4) = make_float4(
            bl(va.z) + bl(u0a.z) + bl(u1a.z) + bl(u2a.z),
            bh(va.z) + bh(u0a.z) + bh(u1a.z) + bh(u2a.z),
            bl(va.w) + bl(u0a.w) + bl(u1a.w) + bl(u2a.w),
            bh(va.w) + bh(u0a.w) + bh(u1a.w) + bh(u2a.w));
        *(float4*)(vp + 8) = make_float4(
            bl(vb.x) + bl(u0b.x) + bl(u1b.x) + bl(u2b.x),
            bh(vb.x) + bh(u0b.x) + bh(u1b.x) + bh(u2b.x),
            bl(vb.y) + bl(u0b.y) + bl(u1b.y) + bl(u2b.y),
            bh(vb.y) + bh(u0b.y) + bh(u1b.y) + bh(u2b.y));
        *(float4*)(vp + 12) = make_float4(
            bl(vb.z) + bl(u0b.z) + bl(u1b.z) + bl(u2b.z),
            bh(vb.z) + bh(u0b.z) + bh(u1b.z) + bh(u2b.z),
            bl(vb.w) + bl(u0b.w) + bl(u1b.w) + bl(u2b.w),
            bh(vb.w) + bh(u0b.w) + bh(u1b.w) + bh(u2b.w));
    }

    // ---- score: all packed-fp16 dot2; independent acc chains
    float a;
    {
        float x0 = dot2(qa.x, ka.x, 0.f), x1 = dot2(qa.y, ka.y, 0.f);
        x0 = dot2(qa.z, ka.z, x0); x1 = dot2(qa.w, ka.w, x1);
        x0 = dot2(qb.x, kb.x, x0); x1 = dot2(qb.y, kb.y, x1);
        x0 = dot2(qb.z, kb.z, x0); x1 = dot2(qb.w, kb.w, x1);

        float bias = 0.f;
#define BIAS_C(ROW)                                                            \
        {                                                                      \
            const ushort* tqp = rq + (size_t)(ROW) * 96 + h * 16;              \
            const ushort* tkp = rk + (size_t)(ROW) * 96 + h * 16;              \
            uint4 ta = *(const uint4*)tqp, tb = *(const uint4*)(tqp + 8);      \
            uint4 ua = *(const uint4*)tkp, ub = *(const uint4*)(tkp + 8);      \
            float u = dot2(qa.x, ta.x, 0.f), w = dot2(ka.x, ua.x, 0.f);        \
            u = dot2(qa.y, ta.y, u); w = dot2(ka.y, ua.y, w);                  \
            u = dot2(qa.z, ta.z, u); w = dot2(ka.z, ua.z, w);                  \
            u = dot2(qa.w, ta.w, u); w = dot2(ka.w, ua.w, w);                  \
            u = dot2(qb.x, tb.x, u); w = dot2(kb.x, ub.x, w);                  \
            u = dot2(qb.y, tb.y, u); w = dot2(kb.y, ub.y, w);                  \
            u = dot2(qb.z, tb.z, u); w = dot2(kb.z, ub.z, w);                  \
            u = dot2(qb.w, tb.w, u); w = dot2(kb.w, ub.w, w);                  \
            bias += u + w;                                                     \
        }
        BIAS_C(i0)
        BIAS_C(64 + i1)
        BIAS_C(128 + i2)
#undef BIAS_C
        a = x0 + x1 + bias;
    }

    // ---- width-16 shuffle softmax
    {
        float mx = a;
#pragma unroll
        for (int off = 8; off >= 1; off >>= 1) mx = fmaxf(mx, __shfl_xor(mx, off, 16));
        float ex = __expf(a - mx);
        float sum = ex;
#pragma unroll
        for (int off = 8; off >= 1; off >>= 1) sum += __shfl_xor(sum, off, 16);
        smw[s][h][e] = ex * __builtin_amdgcn_rcpf(sum);  // rcp: ~1ulp, fine for sm
    }
    __syncthreads();

    // ---- output: float4 smw + pure LDS-FMA column walk, emit bf16 x
    if (active) {
        const float4* wp = (const float4*)smw[s][h];
        float4 w0 = wp[0], w1 = wp[1], w2 = wp[2], w3 = wp[3];
        const float* col = &vs[s][0][tp];
        float x = w0.x * col[0]    + w0.y * col[100]  + w0.z * col[200]  + w0.w * col[300];
        x      += w1.x * col[400]  + w1.y * col[500]  + w1.z * col[600]  + w1.w * col[700];
        x      += w2.x * col[800]  + w2.y * col[900]  + w2.z * col[1000] + w2.w * col[1100];
        x      += w3.x * col[1200] + w3.y * col[1300] + w3.z * col[1400] + w3.w * col[1500];
        xout[(size_t)p * 96 + tp] = f2bf(x);
    }
}

// ---------------------------------------------------------------- launch
extern "C" void kernel_launch(void* const* d_in, const int* in_sizes, int n_in,
                              void* d_out, int out_size, void* d_ws, size_t ws_size,
                              hipStream_t stream) {
    const float* feats   = (const float*)d_in[0];
    const float* xyz     = (const float*)d_in[1];
    const int*   index_1 = (const int*)d_in[5];
    const float* shiftp  = (const float*)d_in[6];
    const float* W_qkv   = (const float*)d_in[7];
    const float* b_qkv   = (const float*)d_in[8];
    const float* table_q = (const float*)d_in[9];
    const float* table_k = (const float*)d_in[10];
    const float* table_v = (const float*)d_in[11];
    const float* W_proj  = (const float*)d_in[12];
    const float* b_proj  = (const float*)d_in[13];
    float* out = (float*)d_out;

    const int n = in_sizes[0] / 96;  // 50000

    float* w = (float*)d_ws;
    float*  mn     = w;                         // 16 floats
    ushort* qbf    = (ushort*)(w + 16);         // n*96 fp16 (pre-scaled q)
    ushort* kvbuf  = qbf + (size_t)n * 96;      // n*192: k fp16 | v bf16
    ushort* xbuf   = kvbuf + (size_t)n * 192;   // n*96 bf16
    ushort* wtqkv  = xbuf + (size_t)n * 96;     // 27648
    ushort* wtproj = wtqkv + 27648;             // 9216
    ushort* rq     = wtproj + 9216;             // 18432 each
    ushort* rk     = rq + 18432;
    ushort* rv     = rk + 18432;

    const int GB = (n + 127) / 128;

    prep_kernel<<<108, 256, 0, stream>>>(W_qkv, W_proj, table_q, table_k, table_v,
                                         wtqkv, wtproj, rq, rk, rv, mn);
    min_reduce_kernel<<<256, 256, 0, stream>>>(xyz, n, mn);
    qkv_mfma_kernel<<<dim3(GB, 3), 256, 0, stream>>>(feats, wtqkv, b_qkv,
                                                     (uint4*)qbf, (uint4*)kvbuf, n);
    attn_kernel<<<(n + 1) / 2, 192, 0, stream>>>(qbf, kvbuf, xyz, index_1, rq, rk,
                                                 rv, mn, shiftp, xbuf, n);
    proj_mfma_kernel<<<GB, 256, 0, stream>>>(xbuf, wtproj, b_proj, out, n);
}

// Round 4
// 263.243 us; speedup vs baseline: 1.1939x; 1.1939x over previous
//
#include <hip/hip_runtime.h>
#include <hip/hip_fp16.h>
#include <math.h>

#define FLT_BIG 3.402823466e38f
typedef unsigned int uint;
typedef unsigned short ushort;
typedef __attribute__((ext_vector_type(8))) _Float16 half8;  // 8 fp16 (4 VGPRs)
typedef __attribute__((ext_vector_type(4))) float floatx4;   // MFMA C/D frag

__device__ inline ushort f2h(float f) {   // fp16 RNE, 1 instr (v_cvt_f16_f32)
    return __half_as_ushort(__float2half(f));
}
// packed 2xfp16 dot with f32 accumulate: d = a.h0*b.h0 + a.h1*b.h1 + c
__device__ inline float dot2(uint a, uint b, float c) {
    float d;
    asm("v_dot2_f32_f16 %0, %1, %2, %3" : "=v"(d) : "v"(a), "v"(b), "v"(c));
    return d;
}

// ---------------------------------------------------------------- min(xyz)
__global__ void min_reduce_kernel(const float* __restrict__ xyz, int n, float* mn) {
    float m0 = FLT_BIG, m1 = FLT_BIG, m2 = FLT_BIG;
    for (int i = blockIdx.x * blockDim.x + threadIdx.x; i < n; i += gridDim.x * blockDim.x) {
        m0 = fminf(m0, xyz[3 * i + 0]);
        m1 = fminf(m1, xyz[3 * i + 1]);
        m2 = fminf(m2, xyz[3 * i + 2]);
    }
#pragma unroll
    for (int off = 32; off > 0; off >>= 1) {
        m0 = fminf(m0, __shfl_down(m0, off));
        m1 = fminf(m1, __shfl_down(m1, off));
        m2 = fminf(m2, __shfl_down(m2, off));
    }
    if ((threadIdx.x & 63) == 0) {
        // xyz >= 0 so float bits are monotone under signed int compare
        atomicMin((int*)&mn[0], __float_as_int(m0));
        atomicMin((int*)&mn[1], __float_as_int(m1));
        atomicMin((int*)&mn[2], __float_as_int(m2));
    }
}

// ---------------------------------------------------------------- prep (small)
// mn init; tables [idx][hd][c] -> [c][idx][hd] fp16; W transposes -> fp16.
__global__ void prep_kernel(const float* __restrict__ W_qkv,
                            const float* __restrict__ W_proj,
                            const float* __restrict__ tq, const float* __restrict__ tk,
                            const float* __restrict__ tv,
                            ushort* __restrict__ wtqkv, ushort* __restrict__ wtproj,
                            ushort* __restrict__ rq, ushort* __restrict__ rk,
                            ushort* __restrict__ rv, float* mn) {
    int tid = blockIdx.x * 256 + threadIdx.x;
    if (tid < 3) mn[tid] = FLT_BIG;
    if (tid < 18432) {  // tables: 3*64*96
        int c = tid / 6144, rem = tid - c * 6144;
        int idx = rem / 96, hd = rem - idx * 96;
        int src = (idx * 96 + hd) * 3 + c;
        rq[tid] = f2h(tq[src]);
        rk[tid] = f2h(tk[src]);
        rv[tid] = f2h(tv[src]);
    }
    if (tid < 27648) {  // WT_qkv[j][d] = W_qkv[d][j], j over 288
        int j = tid / 96, d = tid - j * 96;
        wtqkv[tid] = f2h(W_qkv[d * 288 + j]);
    }
    if (tid < 9216) {  // WT_proj[j][d] = W_proj[d][j]
        int j = tid / 96, d = tid - j * 96;
        wtproj[tid] = f2h(W_proj[d * 96 + j]);
    }
}

// ---------------------------------------------------------------- QKV MFMA GEMM
// feats fp32 (n x 96) @ WT^T + bias, all-fp16 MFMA (q x0.25). Also: ch==0
// blocks compute packed quantized coords xq[p] (3 bytes in a uint), hoisting
// the fmod/floor + xyz loads out of the attn kernel (mn ready: min_reduce
// runs before this kernel in stream order).
__global__ __launch_bounds__(256) void qkv_mfma_kernel(
    const float* __restrict__ A, const ushort* __restrict__ WT,
    const float* __restrict__ bias, uint4* __restrict__ qout4,
    uint4* __restrict__ kvout4, const float* __restrict__ xyz,
    const float* __restrict__ mn, const float* __restrict__ shiftp,
    uint* __restrict__ xq, int n) {
    __shared__ ushort lds[4][32 * 112];
    const int wave = threadIdx.x >> 6, lane = threadIdx.x & 63;
    const int ch = blockIdx.y;
    const int m = lane & 15, q = lane >> 4;
    const int row0 = blockIdx.x * 128 + wave * 32;
    if (row0 >= n) return;

    if (ch == 0 && threadIdx.x < 128) {
        int rp = blockIdx.x * 128 + threadIdx.x;
        if (rp < n) {
            float shift = shiftp[0];
            float q0 = floorf(fmodf(xyz[3 * rp + 0] - mn[0] + shift, 4.0f) * 4.0f);
            float q1 = floorf(fmodf(xyz[3 * rp + 1] - mn[1] + shift, 4.0f) * 4.0f);
            float q2 = floorf(fmodf(xyz[3 * rp + 2] - mn[2] + shift, 4.0f) * 4.0f);
            xq[rp] = (uint)(int)q0 | ((uint)(int)q1 << 8) | ((uint)(int)q2 << 16);
        }
    }

    const ushort* wbase = WT + ((size_t)ch * 96 + m) * 96 + q * 8;
    int r0 = row0 + m;      if (r0 > n - 1) r0 = n - 1;
    int r1 = row0 + 16 + m; if (r1 > n - 1) r1 = n - 1;
    const float4* A4 = (const float4*)A;

    floatx4 acc[2][6];
#pragma unroll
    for (int g = 0; g < 2; g++)
#pragma unroll
        for (int ct = 0; ct < 6; ct++) acc[g][ct] = (floatx4){0.f, 0.f, 0.f, 0.f};

#pragma unroll
    for (int kk4 = 0; kk4 < 24; kk4 += 8) {  // k offset in float4 units
        float4 fa = A4[(size_t)r0 * 24 + kk4 + q * 2];
        float4 fb = A4[(size_t)r0 * 24 + kk4 + q * 2 + 1];
        float4 ga = A4[(size_t)r1 * 24 + kk4 + q * 2];
        float4 gb = A4[(size_t)r1 * 24 + kk4 + q * 2 + 1];
        half8 a0, a1;
        a0[0] = (_Float16)fa.x; a0[1] = (_Float16)fa.y; a0[2] = (_Float16)fa.z; a0[3] = (_Float16)fa.w;
        a0[4] = (_Float16)fb.x; a0[5] = (_Float16)fb.y; a0[6] = (_Float16)fb.z; a0[7] = (_Float16)fb.w;
        a1[0] = (_Float16)ga.x; a1[1] = (_Float16)ga.y; a1[2] = (_Float16)ga.z; a1[3] = (_Float16)ga.w;
        a1[4] = (_Float16)gb.x; a1[5] = (_Float16)gb.y; a1[6] = (_Float16)gb.z; a1[7] = (_Float16)gb.w;
#pragma unroll
        for (int ct = 0; ct < 6; ct++) {
            half8 b = *(const half8*)(wbase + ct * 16 * 96 + kk4 * 4);
            acc[0][ct] = __builtin_amdgcn_mfma_f32_16x16x32_f16(a0, b, acc[0][ct], 0, 0, 0);
            acc[1][ct] = __builtin_amdgcn_mfma_f32_16x16x32_f16(a1, b, acc[1][ct], 0, 0, 0);
        }
    }

    ushort* L = lds[wave];
    const float sc = (ch == 0) ? 0.25f : 1.0f;
#pragma unroll
    for (int g = 0; g < 2; g++)
#pragma unroll
        for (int ct = 0; ct < 6; ct++) {
            float bv = bias[ch * 96 + ct * 16 + m];
#pragma unroll
            for (int r = 0; r < 4; r++) {
                int rowl = g * 16 + q * 4 + r;
                L[rowl * 112 + ct * 16 + m] = f2h((acc[g][ct][r] + bv) * sc);
            }
        }
    // wave-internal LDS RAW: compiler inserts lgkmcnt wait, no barrier needed
    const int strideU4 = (ch == 0) ? 12 : 24;
    const int offU4 = (ch == 2) ? 12 : 0;
    uint4* dst = (ch == 0) ? qout4 : kvout4;
#pragma unroll
    for (int i = 0; i < 6; i++) {
        int idx = i * 64 + lane;  // 0..383 over 32 rows x 12 uint4
        int rowl = idx / 12, u4 = idx - rowl * 12;
        int grow = row0 + rowl;
        if (grow < n) {
            uint4 val = *(const uint4*)(L + rowl * 112 + u4 * 8);
            dst[(size_t)grow * strideU4 + offU4 + u4] = val;
        }
    }
}

// ---------------------------------------------------------------- proj MFMA GEMM
// x fp16 (n x 96) @ WT_proj^T + bias -> out fp32. All-fp16 MFMA.
__global__ __launch_bounds__(256) void proj_mfma_kernel(
    const ushort* __restrict__ A, const ushort* __restrict__ WT,
    const float* __restrict__ bias, float* __restrict__ out, int n) {
    const int wave = threadIdx.x >> 6, lane = threadIdx.x & 63;
    const int m = lane & 15, q = lane >> 4;
    const int row0 = blockIdx.x * 128 + wave * 32;
    if (row0 >= n) return;

    const ushort* wbase = WT + (size_t)m * 96 + q * 8;
    int r0 = row0 + m;      if (r0 > n - 1) r0 = n - 1;
    int r1 = row0 + 16 + m; if (r1 > n - 1) r1 = n - 1;

    floatx4 acc[2][6];
#pragma unroll
    for (int g = 0; g < 2; g++)
#pragma unroll
        for (int ct = 0; ct < 6; ct++) acc[g][ct] = (floatx4){0.f, 0.f, 0.f, 0.f};

#pragma unroll
    for (int kk = 0; kk < 96; kk += 32) {
        half8 a0 = *(const half8*)(A + (size_t)r0 * 96 + q * 8 + kk);
        half8 a1 = *(const half8*)(A + (size_t)r1 * 96 + q * 8 + kk);
#pragma unroll
        for (int ct = 0; ct < 6; ct++) {
            half8 b = *(const half8*)(wbase + ct * 16 * 96 + kk);
            acc[0][ct] = __builtin_amdgcn_mfma_f32_16x16x32_f16(a0, b, acc[0][ct], 0, 0, 0);
            acc[1][ct] = __builtin_amdgcn_mfma_f32_16x16x32_f16(a1, b, acc[1][ct], 0, 0, 0);
        }
    }

#pragma unroll
    for (int g = 0; g < 2; g++)
#pragma unroll
        for (int ct = 0; ct < 6; ct++) {
            int col = ct * 16 + m;
            float bv = bias[col];
#pragma unroll
            for (int r = 0; r < 4; r++) {
                int row = row0 + g * 16 + q * 4 + r;
                if (row < n) out[(size_t)row * 96 + col] = acc[g][ct][r] + bv;
            }
        }
}

// ---------------------------------------------------------------- fused attention
// One 768-thread block per CU (grid 512, 140KB LDS). Tables rq/rk/rv (110KB,
// fp16) staged ONCE into LDS with a 16B-slot XOR swizzle (x = ((R>>1)&3)<<4,
// bijective within each 192B row; spreads random-row reads over bank-start
// slots). Loop: 8 points/iter, gathers (index_1 -> kv row, q, xq) REGISTER-
// PREFETCHED one iteration ahead between the two barriers so HBM latency hides
// under the LDS/VALU body. table_v fold accumulates in FP32 (single fp16
// rounding -> accuracy); vs stored packed fp16 (pitch 208B). x out fp16.
#define ATTN_NB 512
#define ATTN_B 8
__global__ __launch_bounds__(768) void attn_kernel(
    const ushort* __restrict__ qh, const ushort* __restrict__ kv,
    const uint* __restrict__ xq, const int* __restrict__ index_1,
    const ushort* __restrict__ rq, const ushort* __restrict__ rk,
    const ushort* __restrict__ rv, ushort* __restrict__ xout, int n) {
    __shared__ uint4 ldsraw[8768];  // 140288 B: rq 0 | rk 36864 | rv 73728 |
    char* Lb = (char*)ldsraw;       // vs16 110592 (8*16*208) | smw 137216 (8*96*4)

    const int t = threadIdx.x;
    const int pt = t / 96, tp = t - pt * 96;
    const int h = tp >> 4, e = tp & 15;

    const int stride = gridDim.x * ATTN_B;
    const int iters = (n + stride - 1) / stride;

    // ---- prefetch state for the current iteration (registers)
    int p, jd;
    uint4 ka, kb, va, vb, qa, qb;
    uint xqp, xqj;
    auto PREF = [&](int it) {
        p = (it * gridDim.x + blockIdx.x) * ATTN_B + pt;
        int pc = p < n ? p : n - 1;
        jd = index_1[(size_t)pc * 16 + e];
        const ushort* row = kv + (size_t)jd * 192;
        ka = *(const uint4*)(row + h * 16);
        kb = *(const uint4*)(row + h * 16 + 8);
        va = *(const uint4*)(row + 96 + h * 16);
        vb = *(const uint4*)(row + 96 + h * 16 + 8);
        const ushort* qrow = qh + (size_t)pc * 96 + h * 16;
        qa = *(const uint4*)qrow;
        qb = *(const uint4*)(qrow + 8);
        xqp = xq[pc];
        xqj = xq[jd];
    };
    PREF(0);

    // ---- stage tables into LDS (swizzled). 6912 16B chunks / 768 thr = 9.
#pragma unroll
    for (int j = 0; j < 9; j++) {
        const uint4* src = (j < 3) ? (const uint4*)rq
                         : (j < 6) ? (const uint4*)rk : (const uint4*)rv;
        int rem = t + (j % 3) * 768;               // chunk within table
        int ROW = rem / 12, slot = rem - ROW * 12; // 12 x 16B per 192B row
        uint4 val = src[rem];
        *(uint4*)(Lb + (j / 3) * 36864 + ROW * 192 +
                  ((slot << 4) ^ (((ROW >> 1) & 3) << 4))) = val;
    }
    __syncthreads();

    // swizzled 32B row-slice read (two 16B halves, independently swizzled)
    auto LD2 = [&](const char* base, int R, uint4& A, uint4& B) {
        int x = ((R >> 1) & 3) << 4;
        const char* rb = base + R * 192;
        A = *(const uint4*)(rb + ((h * 32) ^ x));
        B = *(const uint4*)(rb + ((h * 32 + 16) ^ x));
    };
    auto F2 = [](const uint4& u, int i) -> float2 {
        return __half22float2(((const __half2*)&u)[i]);
    };

    char* vsb_base = Lb + 110592;
    float* smw_base = (float*)(Lb + 137216);

    for (int it = 0; it < iters; it++) {
        // ---- ridx from packed quantized coords
        const int i0 = (int)(xqp & 255u) - (int)(xqj & 255u) + 15;
        const int i1 = (int)((xqp >> 8) & 255u) - (int)((xqj >> 8) & 255u) + 15;
        const int i2 = (int)((xqp >> 16) & 255u) - (int)((xqj >> 16) & 255u) + 15;

        // ---- fold table_v in FP32 (one fp16 rounding at the end), write vs16
        {
            uint4 t0a, t0b, t1a, t1b, t2a, t2b;
            LD2(Lb + 73728, i0, t0a, t0b);
            LD2(Lb + 73728, 64 + i1, t1a, t1b);
            LD2(Lb + 73728, 128 + i2, t2a, t2b);
            uint4 w0, w1;
            __half2* o0 = (__half2*)&w0;
            __half2* o1 = (__half2*)&w1;
#pragma unroll
            for (int i = 0; i < 4; i++) {
                float2 s0 = F2(va, i), s1 = F2(vb, i);
                float2 a0 = F2(t0a, i), a1 = F2(t1a, i), a2 = F2(t2a, i);
                float2 b0 = F2(t0b, i), b1 = F2(t1b, i), b2 = F2(t2b, i);
                s0.x += a0.x + a1.x + a2.x; s0.y += a0.y + a1.y + a2.y;
                s1.x += b0.x + b1.x + b2.x; s1.y += b0.y + b1.y + b2.y;
                o0[i] = __float22half2_rn(s0);
                o1[i] = __float22half2_rn(s1);
            }
            char* vsb = vsb_base + pt * 3328 + e * 208 + h * 32;
            *(uint4*)vsb = w0;
            *(uint4*)(vsb + 16) = w1;
        }

        // ---- score: packed-fp16 dot2 (q.k + bias tables from LDS)
        float a;
        {
            float x0 = dot2(qa.x, ka.x, 0.f), x1 = dot2(qa.y, ka.y, 0.f);
            x0 = dot2(qa.z, ka.z, x0); x1 = dot2(qa.w, ka.w, x1);
            x0 = dot2(qb.x, kb.x, x0); x1 = dot2(qb.y, kb.y, x1);
            x0 = dot2(qb.z, kb.z, x0); x1 = dot2(qb.w, kb.w, x1);
            float bias = 0.f;
#define BIAS_C(ROW)                                                            \
            {                                                                  \
                uint4 ta, tb, ua, ub;                                          \
                LD2(Lb, (ROW), ta, tb);                                        \
                LD2(Lb + 36864, (ROW), ua, ub);                                \
                float u = dot2(qa.x, ta.x, 0.f), w = dot2(ka.x, ua.x, 0.f);    \
                u = dot2(qa.y, ta.y, u); w = dot2(ka.y, ua.y, w);              \
                u = dot2(qa.z, ta.z, u); w = dot2(ka.z, ua.z, w);              \
                u = dot2(qa.w, ta.w, u); w = dot2(ka.w, ua.w, w);              \
                u = dot2(qb.x, tb.x, u); w = dot2(kb.x, ub.x, w);              \
                u = dot2(qb.y, tb.y, u); w = dot2(kb.y, ub.y, w);              \
                u = dot2(qb.z, tb.z, u); w = dot2(kb.z, ub.z, w);              \
                u = dot2(qb.w, tb.w, u); w = dot2(kb.w, ub.w, w);              \
                bias += u + w;                                                 \
            }
            BIAS_C(i0)
            BIAS_C(64 + i1)
            BIAS_C(128 + i2)
#undef BIAS_C
            a = x0 + x1 + bias;
        }

        // ---- width-16 shuffle softmax
        {
            float mx = a;
#pragma unroll
            for (int off = 8; off >= 1; off >>= 1) mx = fmaxf(mx, __shfl_xor(mx, off, 16));
            float ex = __expf(a - mx);
            float sum = ex;
#pragma unroll
            for (int off = 8; off >= 1; off >>= 1) sum += __shfl_xor(sum, off, 16);
            smw_base[pt * 96 + h * 16 + e] = ex * __builtin_amdgcn_rcpf(sum);
        }

        const int op = p;  // store target for the output phase
        __syncthreads();   // vs16 + smw visible

        // ---- prefetch next iteration's gathers (latency hides under output
        //      + barrier + next compute phase)
        if (it + 1 < iters) PREF(it + 1);

        // ---- output: smw float4s x packed-fp16 vs column walk, emit fp16
        {
            const float4* wp = (const float4*)(smw_base + pt * 96 + h * 16);
            float4 w0 = wp[0], w1 = wp[1], w2 = wp[2], w3 = wp[3];
            const char* colb = vsb_base + pt * 3328 + (tp >> 1) * 4;
            const int sh = (tp & 1) * 16;
            float x = 0.f;
#define OUT4(WV, BASE)                                                          \
            {                                                                   \
                uint u0 = *(const uint*)(colb + (BASE + 0) * 208);              \
                uint u1 = *(const uint*)(colb + (BASE + 1) * 208);              \
                uint u2 = *(const uint*)(colb + (BASE + 2) * 208);              \
                uint u3 = *(const uint*)(colb + (BASE + 3) * 208);              \
                x += WV.x * __half2float(__ushort_as_half((ushort)(u0 >> sh))); \
                x += WV.y * __half2float(__ushort_as_half((ushort)(u1 >> sh))); \
                x += WV.z * __half2float(__ushort_as_half((ushort)(u2 >> sh))); \
                x += WV.w * __half2float(__ushort_as_half((ushort)(u3 >> sh))); \
            }
            OUT4(w0, 0) OUT4(w1, 4) OUT4(w2, 8) OUT4(w3, 12)
#undef OUT4
            if (op < n) xout[(size_t)op * 96 + tp] = f2h(x);
        }
        __syncthreads();   // vs16 consumed; safe to overwrite next iter
    }
}

// ---------------------------------------------------------------- launch
extern "C" void kernel_launch(void* const* d_in, const int* in_sizes, int n_in,
                              void* d_out, int out_size, void* d_ws, size_t ws_size,
                              hipStream_t stream) {
    const float* feats   = (const float*)d_in[0];
    const float* xyz     = (const float*)d_in[1];
    const int*   index_1 = (const int*)d_in[5];
    const float* shiftp  = (const float*)d_in[6];
    const float* W_qkv   = (const float*)d_in[7];
    const float* b_qkv   = (const float*)d_in[8];
    const float* table_q = (const float*)d_in[9];
    const float* table_k = (const float*)d_in[10];
    const float* table_v = (const float*)d_in[11];
    const float* W_proj  = (const float*)d_in[12];
    const float* b_proj  = (const float*)d_in[13];
    float* out = (float*)d_out;

    const int n = in_sizes[0] / 96;  // 50000

    float* w = (float*)d_ws;
    float*  mn     = w;                         // 16 floats
    ushort* qbf    = (ushort*)(w + 16);         // n*96 fp16 (pre-scaled q)
    ushort* kvbuf  = qbf + (size_t)n * 96;      // n*192: k fp16 | v fp16
    ushort* xbuf   = kvbuf + (size_t)n * 192;   // n*96 fp16
    ushort* wtqkv  = xbuf + (size_t)n * 96;     // 27648
    ushort* wtproj = wtqkv + 27648;             // 9216
    ushort* rq     = wtproj + 9216;             // 18432 each
    ushort* rk     = rq + 18432;
    ushort* rv     = rk + 18432;
    uint*   xqv    = (uint*)(rv + 18432);       // n packed quantized coords

    const int GB = (n + 127) / 128;

    prep_kernel<<<108, 256, 0, stream>>>(W_qkv, W_proj, table_q, table_k, table_v,
                                         wtqkv, wtproj, rq, rk, rv, mn);
    min_reduce_kernel<<<256, 256, 0, stream>>>(xyz, n, mn);
    qkv_mfma_kernel<<<dim3(GB, 3), 256, 0, stream>>>(feats, wtqkv, b_qkv,
                                                     (uint4*)qbf, (uint4*)kvbuf,
                                                     xyz, mn, shiftp, xqv, n);
    attn_kernel<<<ATTN_NB, 768, 0, stream>>>(qbf, kvbuf, xqv, index_1, rq, rk,
                                             rv, xbuf, n);
    proj_mfma_kernel<<<GB, 256, 0, stream>>>(xbuf, wtproj, b_proj, out, n);
}

// Round 5
// 224.990 us; speedup vs baseline: 1.3969x; 1.1700x over previous
//
#include <hip/hip_runtime.h>
#include <hip/hip_fp16.h>
#include <math.h>

#define FLT_BIG 3.402823466e38f
typedef unsigned int uint;
typedef unsigned short ushort;
typedef __attribute__((ext_vector_type(8))) _Float16 half8;  // 8 fp16 (4 VGPRs)
typedef __attribute__((ext_vector_type(4))) float floatx4;   // MFMA C/D frag

__device__ inline ushort f2h(float f) {   // fp16 RNE, 1 instr (v_cvt_f16_f32)
    return __half_as_ushort(__float2half(f));
}
// packed 2xfp16 dot with f32 accumulate: d = a.h0*b.h0 + a.h1*b.h1 + c
__device__ inline float dot2(uint a, uint b, float c) {
    float d;
    asm("v_dot2_f32_f16 %0, %1, %2, %3" : "=v"(d) : "v"(a), "v"(b), "v"(c));
    return d;
}
// DPP cross-lane read (VALU pipe, not DS). CTRL: 0x120+N=row_ror:N,
// 0x140=row_mirror (xor15), 0x141=row_half_mirror (xor7 within 8),
// 0x4E=quad_perm[2,3,0,1] (xor2), 0xB1=quad_perm[1,0,3,2] (xor1).
template <int CTRL>
__device__ inline float dppf(float x) {
    return __int_as_float(__builtin_amdgcn_update_dpp(
        __float_as_int(x), __float_as_int(x), CTRL, 0xF, 0xF, true));
}

// ---------------------------------------------------------------- min(xyz)
__global__ void min_reduce_kernel(const float* __restrict__ xyz, int n, float* mn) {
    float m0 = FLT_BIG, m1 = FLT_BIG, m2 = FLT_BIG;
    for (int i = blockIdx.x * blockDim.x + threadIdx.x; i < n; i += gridDim.x * blockDim.x) {
        m0 = fminf(m0, xyz[3 * i + 0]);
        m1 = fminf(m1, xyz[3 * i + 1]);
        m2 = fminf(m2, xyz[3 * i + 2]);
    }
#pragma unroll
    for (int off = 32; off > 0; off >>= 1) {
        m0 = fminf(m0, __shfl_down(m0, off));
        m1 = fminf(m1, __shfl_down(m1, off));
        m2 = fminf(m2, __shfl_down(m2, off));
    }
    if ((threadIdx.x & 63) == 0) {
        // xyz >= 0 so float bits are monotone under signed int compare
        atomicMin((int*)&mn[0], __float_as_int(m0));
        atomicMin((int*)&mn[1], __float_as_int(m1));
        atomicMin((int*)&mn[2], __float_as_int(m2));
    }
}

// ---------------------------------------------------------------- prep (small)
// mn init; tables [idx][hd][c] -> [c][idx][hd] fp16; W transposes -> fp16.
__global__ void prep_kernel(const float* __restrict__ W_qkv,
                            const float* __restrict__ W_proj,
                            const float* __restrict__ tq, const float* __restrict__ tk,
                            const float* __restrict__ tv,
                            ushort* __restrict__ wtqkv, ushort* __restrict__ wtproj,
                            ushort* __restrict__ rq, ushort* __restrict__ rk,
                            ushort* __restrict__ rv, float* mn) {
    int tid = blockIdx.x * 256 + threadIdx.x;
    if (tid < 3) mn[tid] = FLT_BIG;
    if (tid < 18432) {  // tables: 3*64*96
        int c = tid / 6144, rem = tid - c * 6144;
        int idx = rem / 96, hd = rem - idx * 96;
        int src = (idx * 96 + hd) * 3 + c;
        rq[tid] = f2h(tq[src]);
        rk[tid] = f2h(tk[src]);
        rv[tid] = f2h(tv[src]);
    }
    if (tid < 27648) {  // WT_qkv[j][d] = W_qkv[d][j], j over 288
        int j = tid / 96, d = tid - j * 96;
        wtqkv[tid] = f2h(W_qkv[d * 288 + j]);
    }
    if (tid < 9216) {  // WT_proj[j][d] = W_proj[d][j]
        int j = tid / 96, d = tid - j * 96;
        wtproj[tid] = f2h(W_proj[d * 96 + j]);
    }
}

// ---------------------------------------------------------------- QKV MFMA GEMM
// feats fp32 (n x 96) @ WT^T + bias, all-fp16 MFMA (q x0.25). Also: ch==0
// blocks compute packed quantized coords xq[p] (3 bytes in a uint), hoisting
// the fmod/floor + xyz loads out of the attn kernel (mn ready: min_reduce
// runs before this kernel in stream order).
__global__ __launch_bounds__(256) void qkv_mfma_kernel(
    const float* __restrict__ A, const ushort* __restrict__ WT,
    const float* __restrict__ bias, uint4* __restrict__ qout4,
    uint4* __restrict__ kvout4, const float* __restrict__ xyz,
    const float* __restrict__ mn, const float* __restrict__ shiftp,
    uint* __restrict__ xq, int n) {
    __shared__ ushort lds[4][32 * 112];
    const int wave = threadIdx.x >> 6, lane = threadIdx.x & 63;
    const int ch = blockIdx.y;
    const int m = lane & 15, q = lane >> 4;
    const int row0 = blockIdx.x * 128 + wave * 32;
    if (row0 >= n) return;

    if (ch == 0 && threadIdx.x < 128) {
        int rp = blockIdx.x * 128 + threadIdx.x;
        if (rp < n) {
            float shift = shiftp[0];
            float q0 = floorf(fmodf(xyz[3 * rp + 0] - mn[0] + shift, 4.0f) * 4.0f);
            float q1 = floorf(fmodf(xyz[3 * rp + 1] - mn[1] + shift, 4.0f) * 4.0f);
            float q2 = floorf(fmodf(xyz[3 * rp + 2] - mn[2] + shift, 4.0f) * 4.0f);
            xq[rp] = (uint)(int)q0 | ((uint)(int)q1 << 8) | ((uint)(int)q2 << 16);
        }
    }

    const ushort* wbase = WT + ((size_t)ch * 96 + m) * 96 + q * 8;
    int r0 = row0 + m;      if (r0 > n - 1) r0 = n - 1;
    int r1 = row0 + 16 + m; if (r1 > n - 1) r1 = n - 1;
    const float4* A4 = (const float4*)A;

    floatx4 acc[2][6];
#pragma unroll
    for (int g = 0; g < 2; g++)
#pragma unroll
        for (int ct = 0; ct < 6; ct++) acc[g][ct] = (floatx4){0.f, 0.f, 0.f, 0.f};

#pragma unroll
    for (int kk4 = 0; kk4 < 24; kk4 += 8) {  // k offset in float4 units
        float4 fa = A4[(size_t)r0 * 24 + kk4 + q * 2];
        float4 fb = A4[(size_t)r0 * 24 + kk4 + q * 2 + 1];
        float4 ga = A4[(size_t)r1 * 24 + kk4 + q * 2];
        float4 gb = A4[(size_t)r1 * 24 + kk4 + q * 2 + 1];
        half8 a0, a1;
        a0[0] = (_Float16)fa.x; a0[1] = (_Float16)fa.y; a0[2] = (_Float16)fa.z; a0[3] = (_Float16)fa.w;
        a0[4] = (_Float16)fb.x; a0[5] = (_Float16)fb.y; a0[6] = (_Float16)fb.z; a0[7] = (_Float16)fb.w;
        a1[0] = (_Float16)ga.x; a1[1] = (_Float16)ga.y; a1[2] = (_Float16)ga.z; a1[3] = (_Float16)ga.w;
        a1[4] = (_Float16)gb.x; a1[5] = (_Float16)gb.y; a1[6] = (_Float16)gb.z; a1[7] = (_Float16)gb.w;
#pragma unroll
        for (int ct = 0; ct < 6; ct++) {
            half8 b = *(const half8*)(wbase + ct * 16 * 96 + kk4 * 4);
            acc[0][ct] = __builtin_amdgcn_mfma_f32_16x16x32_f16(a0, b, acc[0][ct], 0, 0, 0);
            acc[1][ct] = __builtin_amdgcn_mfma_f32_16x16x32_f16(a1, b, acc[1][ct], 0, 0, 0);
        }
    }

    ushort* L = lds[wave];
    const float sc = (ch == 0) ? 0.25f : 1.0f;
#pragma unroll
    for (int g = 0; g < 2; g++)
#pragma unroll
        for (int ct = 0; ct < 6; ct++) {
            float bv = bias[ch * 96 + ct * 16 + m];
#pragma unroll
            for (int r = 0; r < 4; r++) {
                int rowl = g * 16 + q * 4 + r;
                L[rowl * 112 + ct * 16 + m] = f2h((acc[g][ct][r] + bv) * sc);
            }
        }
    // wave-internal LDS RAW: compiler inserts lgkmcnt wait, no barrier needed
    const int strideU4 = (ch == 0) ? 12 : 24;
    const int offU4 = (ch == 2) ? 12 : 0;
    uint4* dst = (ch == 0) ? qout4 : kvout4;
#pragma unroll
    for (int i = 0; i < 6; i++) {
        int idx = i * 64 + lane;  // 0..383 over 32 rows x 12 uint4
        int rowl = idx / 12, u4 = idx - rowl * 12;
        int grow = row0 + rowl;
        if (grow < n) {
            uint4 val = *(const uint4*)(L + rowl * 112 + u4 * 8);
            dst[(size_t)grow * strideU4 + offU4 + u4] = val;
        }
    }
}

// ---------------------------------------------------------------- proj MFMA GEMM
// x fp16 (n x 96) @ WT_proj^T + bias -> out fp32. All-fp16 MFMA.
__global__ __launch_bounds__(256) void proj_mfma_kernel(
    const ushort* __restrict__ A, const ushort* __restrict__ WT,
    const float* __restrict__ bias, float* __restrict__ out, int n) {
    const int wave = threadIdx.x >> 6, lane = threadIdx.x & 63;
    const int m = lane & 15, q = lane >> 4;
    const int row0 = blockIdx.x * 128 + wave * 32;
    if (row0 >= n) return;

    const ushort* wbase = WT + (size_t)m * 96 + q * 8;
    int r0 = row0 + m;      if (r0 > n - 1) r0 = n - 1;
    int r1 = row0 + 16 + m; if (r1 > n - 1) r1 = n - 1;

    floatx4 acc[2][6];
#pragma unroll
    for (int g = 0; g < 2; g++)
#pragma unroll
        for (int ct = 0; ct < 6; ct++) acc[g][ct] = (floatx4){0.f, 0.f, 0.f, 0.f};

#pragma unroll
    for (int kk = 0; kk < 96; kk += 32) {
        half8 a0 = *(const half8*)(A + (size_t)r0 * 96 + q * 8 + kk);
        half8 a1 = *(const half8*)(A + (size_t)r1 * 96 + q * 8 + kk);
#pragma unroll
        for (int ct = 0; ct < 6; ct++) {
            half8 b = *(const half8*)(wbase + ct * 16 * 96 + kk);
            acc[0][ct] = __builtin_amdgcn_mfma_f32_16x16x32_f16(a0, b, acc[0][ct], 0, 0, 0);
            acc[1][ct] = __builtin_amdgcn_mfma_f32_16x16x32_f16(a1, b, acc[1][ct], 0, 0, 0);
        }
    }

#pragma unroll
    for (int g = 0; g < 2; g++)
#pragma unroll
        for (int ct = 0; ct < 6; ct++) {
            int col = ct * 16 + m;
            float bv = bias[col];
#pragma unroll
            for (int r = 0; r < 4; r++) {
                int row = row0 + g * 16 + q * 4 + r;
                if (row < n) out[(size_t)row * 96 + col] = acc[g][ct][r] + bv;
            }
        }
}

// ---------------------------------------------------------------- fused attention
// One 768-thread block per CU (grid 256, 110KB LDS = tables only). Tables
// staged once (swizzled). Per iteration (8 points): table reads are the ONLY
// DS ops (18 x b128/thread); softmax reduce = DPP rotations (VALU pipe); the
// PV transpose-reduce = DPP butterfly over masks {15,7,2,1} with keep-bits
// c3=e3,c2=e2,c1=e1,c0=e0 -> lane e ends with column e (identity store).
// v stays FP32 in registers end-to-end (no vs fp16 rounding -> accuracy).
// ZERO barriers in the loop; 2-stage register prefetch (index -> rows) breaks
// the dependent-HBM chain and hides under free-running waves.
#define ATTN_NB 256
#define ATTN_B 8
__global__ __launch_bounds__(768) void attn_kernel(
    const ushort* __restrict__ qh, const ushort* __restrict__ kv,
    const uint* __restrict__ xq, const int* __restrict__ index_1,
    const ushort* __restrict__ rq, const ushort* __restrict__ rk,
    const ushort* __restrict__ rv, ushort* __restrict__ xout, int n) {
    __shared__ uint4 ldsraw[6912];  // 110592 B: rq 0 | rk 36864 | rv 73728
    char* Lb = (char*)ldsraw;

    const int t = threadIdx.x;
    const int pt = t / 96, tp = t - pt * 96;
    const int h = tp >> 4, e = tp & 15;

    const int stride = gridDim.x * ATTN_B;                 // 2048
    const int iters = (n + stride - 1) / stride;           // 25

    // ---- 2-stage prefetch state
    int pA, jdA; uint xqpA;                                // stage A: indices
    auto PREF_A = [&](int it) {
        pA = (it * gridDim.x + blockIdx.x) * ATTN_B + pt;
        int pc = pA < n ? pA : n - 1;
        jdA = index_1[(size_t)pc * 16 + e];
        xqpA = xq[pc];
    };
    int p, jd; uint xqp, xqj;                              // stage B: rows
    uint4 ka, kb, va, vb, qa, qb;
    auto PREF_B = [&]() {
        p = pA; jd = jdA; xqp = xqpA;
        int pc = p < n ? p : n - 1;
        const ushort* row = kv + (size_t)jd * 192;
        ka = *(const uint4*)(row + h * 16);
        kb = *(const uint4*)(row + h * 16 + 8);
        va = *(const uint4*)(row + 96 + h * 16);
        vb = *(const uint4*)(row + 96 + h * 16 + 8);
        const ushort* qrow = qh + (size_t)pc * 96 + h * 16;
        qa = *(const uint4*)qrow;
        qb = *(const uint4*)(qrow + 8);
        xqj = xq[jd];
    };
    PREF_A(0); PREF_B(); PREF_A(1);

    // ---- stage tables into LDS (swizzled). 6912 16B chunks / 768 thr = 9.
#pragma unroll
    for (int j = 0; j < 9; j++) {
        const uint4* src = (j < 3) ? (const uint4*)rq
                         : (j < 6) ? (const uint4*)rk : (const uint4*)rv;
        int rem = t + (j % 3) * 768;               // chunk within table
        int ROW = rem / 12, slot = rem - ROW * 12; // 12 x 16B per 192B row
        uint4 val = src[rem];
        *(uint4*)(Lb + (j / 3) * 36864 + ROW * 192 +
                  ((slot << 4) ^ (((ROW >> 1) & 3) << 4))) = val;
    }
    __syncthreads();

    // swizzled 32B row-slice read (two 16B halves, independently swizzled)
    auto LD2 = [&](const char* base, int R, uint4& A, uint4& B) {
        int x = ((R >> 1) & 3) << 4;
        const char* rb = base + R * 192;
        A = *(const uint4*)(rb + ((h * 32) ^ x));
        B = *(const uint4*)(rb + ((h * 32 + 16) ^ x));
    };
    auto F2 = [](const uint4& u, int i) -> float2 {
        return __half22float2(((const __half2*)&u)[i]);
    };

    const bool b3 = (e & 8) != 0, b2 = (e & 4) != 0;
    const bool b1 = (e & 2) != 0, b0 = (e & 1) != 0;

    for (int it = 0; it < iters; it++) {
        // ---- ridx from packed quantized coords
        const int i0 = (int)(xqp & 255u) - (int)(xqj & 255u) + 15;
        const int i1 = (int)((xqp >> 8) & 255u) - (int)((xqj >> 8) & 255u) + 15;
        const int i2 = (int)((xqp >> 16) & 255u) - (int)((xqj >> 16) & 255u) + 15;

        // ---- unpack v row to fp32 (frees va/vb for the prefetch)
        float f[16];
#pragma unroll
        for (int i = 0; i < 4; i++) {
            float2 lo = F2(va, i), hi = F2(vb, i);
            f[2 * i] = lo.x; f[2 * i + 1] = lo.y;
            f[8 + 2 * i] = hi.x; f[8 + 2 * i + 1] = hi.y;
        }

        // ---- score: packed-fp16 dot2 (q.k + bias tables from LDS)
        float a;
        {
            float x0 = dot2(qa.x, ka.x, 0.f), x1 = dot2(qa.y, ka.y, 0.f);
            x0 = dot2(qa.z, ka.z, x0); x1 = dot2(qa.w, ka.w, x1);
            x0 = dot2(qb.x, kb.x, x0); x1 = dot2(qb.y, kb.y, x1);
            x0 = dot2(qb.z, kb.z, x0); x1 = dot2(qb.w, kb.w, x1);
            float bias = 0.f;
#define BIAS_C(ROW)                                                            \
            {                                                                  \
                uint4 ta, tb, ua, ub;                                          \
                LD2(Lb, (ROW), ta, tb);                                        \
                LD2(Lb + 36864, (ROW), ua, ub);                                \
                float u = dot2(qa.x, ta.x, 0.f), w = dot2(ka.x, ua.x, 0.f);    \
                u = dot2(qa.y, ta.y, u); w = dot2(ka.y, ua.y, w);              \
                u = dot2(qa.z, ta.z, u); w = dot2(ka.z, ua.z, w);              \
                u = dot2(qa.w, ta.w, u); w = dot2(ka.w, ua.w, w);              \
                u = dot2(qb.x, tb.x, u); w = dot2(kb.x, ub.x, w);              \
                u = dot2(qb.y, tb.y, u); w = dot2(kb.y, ub.y, w);              \
                u = dot2(qb.z, tb.z, u); w = dot2(kb.z, ub.z, w);              \
                u = dot2(qb.w, tb.w, u); w = dot2(kb.w, ub.w, w);              \
                bias += u + w;                                                 \
            }
            BIAS_C(i0)
            BIAS_C(64 + i1)
            BIAS_C(128 + i2)
#undef BIAS_C
            a = x0 + x1 + bias;
        }

        const int op = p;  // capture store target before prefetch overwrites
        if (it + 1 < iters) { PREF_B(); PREF_A(it + 2); }

        // ---- fold table_v into f (fp32 accumulate, LDS reads only)
        {
            uint4 t0a, t0b, t1a, t1b, t2a, t2b;
            LD2(Lb + 73728, i0, t0a, t0b);
            LD2(Lb + 73728, 64 + i1, t1a, t1b);
            LD2(Lb + 73728, 128 + i2, t2a, t2b);
#pragma unroll
            for (int i = 0; i < 4; i++) {
                float2 a0 = F2(t0a, i), a1 = F2(t1a, i), a2 = F2(t2a, i);
                f[2 * i]     += a0.x + a1.x + a2.x;
                f[2 * i + 1] += a0.y + a1.y + a2.y;
                float2 c0 = F2(t0b, i), c1 = F2(t1b, i), c2 = F2(t2b, i);
                f[8 + 2 * i]     += c0.x + c1.x + c2.x;
                f[8 + 2 * i + 1] += c0.y + c1.y + c2.y;
            }
        }

        // ---- softmax over the 16-lane group via DPP rotations (no LDS)
        float wgt;
        {
            float mx = a;
            mx = fmaxf(mx, dppf<0x128>(mx));   // ror 8
            mx = fmaxf(mx, dppf<0x124>(mx));   // ror 4
            mx = fmaxf(mx, dppf<0x122>(mx));   // ror 2
            mx = fmaxf(mx, dppf<0x121>(mx));   // ror 1
            float ex = __expf(a - mx);
            float sum = ex;
            sum += dppf<0x128>(sum);
            sum += dppf<0x124>(sum);
            sum += dppf<0x122>(sum);
            sum += dppf<0x121>(sum);
            wgt = ex * __builtin_amdgcn_rcpf(sum);
        }

        // ---- PV: DPP butterfly transpose-reduce; lane e ends with col e
        float P[16];
#pragma unroll
        for (int c = 0; c < 16; c++) P[c] = wgt * f[c];
        float A8[8];
#pragma unroll
        for (int j = 0; j < 8; j++) {          // xor15 (mirror), keep c3=e3
            float kp = b3 ? P[j + 8] : P[j];
            float sd = b3 ? P[j] : P[j + 8];
            A8[j] = kp + dppf<0x140>(sd);
        }
        float B4[4];
#pragma unroll
        for (int j = 0; j < 4; j++) {          // xor7 (half_mirror), keep c2=e2
            float kp = b2 ? A8[j + 4] : A8[j];
            float sd = b2 ? A8[j] : A8[j + 4];
            B4[j] = kp + dppf<0x141>(sd);
        }
        float C2[2];
#pragma unroll
        for (int j = 0; j < 2; j++) {          // xor2 (quad_perm), keep c1=e1
            float kp = b1 ? B4[j + 2] : B4[j];
            float sd = b1 ? B4[j] : B4[j + 2];
            C2[j] = kp + dppf<0x4E>(sd);
        }
        {                                      // xor1 (quad_perm), keep c0=e0
            float kp = b0 ? C2[1] : C2[0];
            float sd = b0 ? C2[0] : C2[1];
            float xres = kp + dppf<0xB1>(sd);
            if (op < n) xout[(size_t)op * 96 + tp] = f2h(xres);
        }
    }
}

// ---------------------------------------------------------------- launch
extern "C" void kernel_launch(void* const* d_in, const int* in_sizes, int n_in,
                              void* d_out, int out_size, void* d_ws, size_t ws_size,
                              hipStream_t stream) {
    const float* feats   = (const float*)d_in[0];
    const float* xyz     = (const float*)d_in[1];
    const int*   index_1 = (const int*)d_in[5];
    const float* shiftp  = (const float*)d_in[6];
    const float* W_qkv   = (const float*)d_in[7];
    const float* b_qkv   = (const float*)d_in[8];
    const float* table_q = (const float*)d_in[9];
    const float* table_k = (const float*)d_in[10];
    const float* table_v = (const float*)d_in[11];
    const float* W_proj  = (const float*)d_in[12];
    const float* b_proj  = (const float*)d_in[13];
    float* out = (float*)d_out;

    const int n = in_sizes[0] / 96;  // 50000

    float* w = (float*)d_ws;
    float*  mn     = w;                         // 16 floats
    ushort* qbf    = (ushort*)(w + 16);         // n*96 fp16 (pre-scaled q)
    ushort* kvbuf  = qbf + (size_t)n * 96;      // n*192: k fp16 | v fp16
    ushort* xbuf   = kvbuf + (size_t)n * 192;   // n*96 fp16
    ushort* wtqkv  = xbuf + (size_t)n * 96;     // 27648
    ushort* wtproj = wtqkv + 27648;             // 9216
    ushort* rq     = wtproj + 9216;             // 18432 each
    ushort* rk     = rq + 18432;
    ushort* rv     = rk + 18432;
    uint*   xqv    = (uint*)(rv + 18432);       // n packed quantized coords

    const int GB = (n + 127) / 128;

    prep_kernel<<<108, 256, 0, stream>>>(W_qkv, W_proj, table_q, table_k, table_v,
                                         wtqkv, wtproj, rq, rk, rv, mn);
    min_reduce_kernel<<<256, 256, 0, stream>>>(xyz, n, mn);
    qkv_mfma_kernel<<<dim3(GB, 3), 256, 0, stream>>>(feats, wtqkv, b_qkv,
                                                     (uint4*)qbf, (uint4*)kvbuf,
                                                     xyz, mn, shiftp, xqv, n);
    attn_kernel<<<ATTN_NB, 768, 0, stream>>>(qbf, kvbuf, xqv, index_1, rq, rk,
                                             rv, xbuf, n);
    proj_mfma_kernel<<<GB, 256, 0, stream>>>(xbuf, wtproj, b_proj, out, n);
}